// Round 8
// baseline (349.187 us; speedup 1.0000x reference)
//
#include <hip/hip_runtime.h>
#include <cstdint>
#include <cstddef>
#include <type_traits>

#define B_ROWS 16384
#define D_DIM  512
#define O_DIM  512
#define K_DIM  4608    // 9 * 512: f=0 silu (base), f=1..8 spline channels
#define BM 32          // b-rows per block; block covers ALL 512 o-cols

typedef __bf16 bf16;
typedef __attribute__((ext_vector_type(8))) bf16  bf16x8;
typedef __attribute__((ext_vector_type(4))) float f32x4;

__device__ __forceinline__ uint32_t pk2(float a, float b) {
    uint16_t ua = __builtin_bit_cast(uint16_t, (__bf16)a);
    uint16_t ub = __builtin_bit_cast(uint16_t, (__bf16)b);
    return (uint32_t)ua | ((uint32_t)ub << 16);
}

// Spline channels b0..b7 for one element as 4 packed bf16 pair-regs.
// out[j] = w_{j-s}, s = j0-3: 128-bit shift of [w3:w2:w1:w0] by 16*s bits
// (s in 0..10; s>=8 -> all zero, matches ref truncation for x>=1.2).
__device__ __forceinline__ void spline_pairs(float xv, uint32_t out[4]) {
    float xn = fminf(fmaxf(xv, -2.0f), 2.0f);
    float t  = (xn + 3.2f) * 2.5f;        // in [3,13]
    int   j0 = (int)t;                    // t>0 so trunc==floor
    float u  = t - (float)j0;
    float u2 = u * u, u3 = u2 * u, omu = 1.0f - u;
    const float s6 = 1.0f / 6.0f;
    float w0 = omu * omu * omu * s6;
    float w1 = (3.0f * u3 - 6.0f * u2 + 4.0f) * s6;
    float w2 = (-3.0f * u3 + 3.0f * u2 + 3.0f * u + 1.0f) * s6;
    float w3 = u3 * s6;
    uint64_t W64 = ((uint64_t)pk2(w2, w3) << 32) | pk2(w0, w1);
    int sh = (j0 - 3) * 16;               // 0..160
    uint64_t lo = W64 << (sh & 63);
    uint64_t hi = W64 >> ((64 - sh) & 63);
    uint32_t lo_lo = (uint32_t)lo, lo_hi = (uint32_t)(lo >> 32);
    uint32_t hi_lo = (uint32_t)hi, hi_hi = (uint32_t)(hi >> 32);
    bool lt64 = sh < 64, eq0 = (sh == 0), lt128 = sh < 128;
    out[0] = lt64 ? lo_lo : 0u;
    out[1] = lt64 ? lo_hi : 0u;
    out[2] = lt64 ? (eq0 ? 0u : hi_lo) : (lt128 ? lo_lo : 0u);
    out[3] = lt64 ? (eq0 ? 0u : hi_hi) : (lt128 ? lo_hi : 0u);
}

// base_weight[O,D] + spline_weight[O,D,8] fp32 -> W[O, 4608] bf16, k = f*512 + i
__global__ void pack_w_kernel(const float* __restrict__ bw,
                              const float* __restrict__ sw,
                              bf16* __restrict__ W) {
    int idx = blockIdx.x * blockDim.x + threadIdx.x;   // over O*64
    if (idx >= O_DIM * 64) return;
    int o  = idx >> 6;
    int i0 = (idx & 63) * 8;

    bf16 ob[9][8];
    const float* bwp = bw + (size_t)o * D_DIM + i0;
#pragma unroll
    for (int e = 0; e < 8; e++) {
        ob[0][e] = (bf16)bwp[e];
        const float* sp = sw + ((size_t)o * D_DIM + i0 + e) * 8;
#pragma unroll
        for (int c = 0; c < 8; c++)
            ob[c + 1][e] = (bf16)sp[c];
    }
    bf16* row = W + (size_t)o * K_DIM + i0;
#pragma unroll
    for (int f = 0; f < 9; f++)
        *(bf16x8*)(row + (size_t)f * D_DIM) = *(const bf16x8*)ob[f];
}

// Fused KAN GEMM, R8: LDS was the wall (R5==R7 at ~76% LDS busy).
// - W (B-operand) loaded global->register, double-buffered: no Bs LDS at all.
// - Block = 32 b x 512 o (8 waves of 32b x 64o): featurize redundancy = 1,
//   As = 2 x 2 KB; LDS per block-step drops 68 KB -> 18 KB.
// - 1 barrier/step (guards only the tiny As); XOR-swizzled As slots.
__global__ __launch_bounds__(512, 4)
void gemm_fused_kernel(const float* __restrict__ x, const bf16* __restrict__ W,
                       float* __restrict__ C) {
    __shared__ __align__(16) bf16 As[2][BM * 32];    // 2 x 2 KB

    const int tid  = threadIdx.x;
    const int m0   = blockIdx.x * BM;
    const int wave = tid >> 6;           // 0..7
    const int lane = tid & 63;
    const int wn   = wave * 64;          // wave o-range
    const int l15  = lane & 15;
    const int quad = lane >> 4;

    // featurize ownership: row r (0..31), element-pair ip (0..15):
    // i = c*32 + ip*2 + {0,1}; one uint32 (2 bf16) ds_write per step.
    const int r  = tid >> 4;
    const int ip = tid & 15;
    const float* xp = x + (size_t)(m0 + r) * D_DIM + ip * 2;
    // phys 16B-window = logical(ip>>2) ^ ((r>>1)&3); +((ip&3)*2) within window
    const int awo = r * 32 + (((ip >> 2) ^ ((r >> 1) & 3)) << 3) + (ip & 3) * 2;

    // W per-lane fragment pointers (col = wn + jn*16 + l15, k-base quad*8)
    const bf16* wp0 = W + (size_t)(wn +  0 + l15) * K_DIM + quad * 8;
    const bf16* wp1 = W + (size_t)(wn + 16 + l15) * K_DIM + quad * 8;
    const bf16* wp2 = W + (size_t)(wn + 32 + l15) * K_DIM + quad * 8;
    const bf16* wp3 = W + (size_t)(wn + 48 + l15) * K_DIM + quad * 8;

    // As reader: row tt*16+l15, phys window = quad ^ ((l15>>1)&3)
    // (row>>1 term: (tt*16)>>1 = 8tt == 0 mod 4 -> fragment-invariant)
    const int aoff = l15 * 32 + ((quad ^ ((l15 >> 1) & 3)) << 3);

    f32x4 acc[2][4] = {};
    bf16x8 wfr[2][4];        // W fragment double-buffer (registers)
    uint32_t vpk[2][2][4];   // [chunk parity][element][channel-pair]
    float xe[2];

    // ---- prologue: chunk 0 features + step-(0,0) operands ----
    {
        float2 xv = *(const float2*)xp;
        xe[0] = xv.x; xe[1] = xv.y;
        spline_pairs(xe[0], vpk[0][0]);
        spline_pairs(xe[1], vpk[0][1]);
        float s0 = xe[0] * __builtin_amdgcn_rcpf(1.0f + __expf(-xe[0]));
        float s1 = xe[1] * __builtin_amdgcn_rcpf(1.0f + __expf(-xe[1]));
        *(uint32_t*)&As[0][awo] = pk2(s0, s1);
        wfr[0][0] = *(const bf16x8*)wp0;   // koff = 0: feature 0, chunk 0
        wfr[0][1] = *(const bf16x8*)wp1;
        wfr[0][2] = *(const bf16x8*)wp2;
        wfr[0][3] = *(const bf16x8*)wp3;
    }
    __syncthreads();

    auto chunk_body = [&](auto pcv, int c) {
        constexpr int PC = decltype(pcv)::value;   // chunk parity
#pragma unroll
        for (int f = 0; f < 9; f++) {
            const int cur = (PC + f) & 1;          // step buffer parity
            const int nxt = cur ^ 1;
            const bool haveNext = !(c == 15 && f == 8);

            // prefetch W fragments for next step (full step of flight)
            if (haveNext) {
                const int koff = (f < 8) ? ((f + 1) * D_DIM + c * 32)
                                         : ((c + 1) * 32);
                wfr[nxt][0] = *(const bf16x8*)(wp0 + koff);
                wfr[nxt][1] = *(const bf16x8*)(wp1 + koff);
                wfr[nxt][2] = *(const bf16x8*)(wp2 + koff);
                wfr[nxt][3] = *(const bf16x8*)(wp3 + koff);
            }
            // x prefetch for chunk c+1 (chunk c's xe dead after its silu)
            if (f == 0 && c < 15) {
                float2 xv = *(const float2*)(xp + (c + 1) * 32);
                xe[0] = xv.x; xe[1] = xv.y;
            }
            // pipelined featurize of chunk c+1: one element at f=1,2
            if ((f == 1 || f == 2) && c < 15)
                spline_pairs(xe[f - 1], vpk[PC ^ 1][f - 1]);
            // As write for NEXT step: feature f+1 (= spline channel f) of
            // chunk c, or feature 0 (silu) of chunk c+1 at f==8
            if (haveNext) {
                uint32_t o;
                if (f < 8) {
                    uint32_t lo = vpk[PC][0][f >> 1], hi = vpk[PC][1][f >> 1];
                    o = (f & 1) ? ((lo >> 16) | (hi & 0xFFFF0000u))
                                : ((lo & 0xFFFFu) | (hi << 16));
                } else {
                    float s0 = xe[0] * __builtin_amdgcn_rcpf(1.0f + __expf(-xe[0]));
                    float s1 = xe[1] * __builtin_amdgcn_rcpf(1.0f + __expf(-xe[1]));
                    o = pk2(s0, s1);
                }
                *(uint32_t*)&As[nxt][awo] = o;
            }

            // consume: A from LDS, W from registers
            bf16x8 af[2];
            af[0] = *(const bf16x8*)(&As[cur][aoff]);
            af[1] = *(const bf16x8*)(&As[cur][aoff + 512]);
#pragma unroll
            for (int tt = 0; tt < 2; tt++)
#pragma unroll
                for (int jn = 0; jn < 4; jn++)
                    acc[tt][jn] = __builtin_amdgcn_mfma_f32_16x16x32_bf16(
                        af[tt], wfr[cur][jn], acc[tt][jn], 0, 0, 0);
            __syncthreads();
        }
    };

    for (int cc = 0; cc < 16; cc += 2) {
        chunk_body(std::integral_constant<int,0>{}, cc);
        chunk_body(std::integral_constant<int,1>{}, cc + 1);
    }

    // C/D layout: col = lane&15, row = quad*4 + reg   [measured m89/m91]
#pragma unroll
    for (int tt = 0; tt < 2; tt++) {
        const int rbase = m0 + tt * 16 + quad * 4;
#pragma unroll
        for (int jn = 0; jn < 4; jn++) {
            const int col = wn + jn * 16 + l15;
#pragma unroll
            for (int rr = 0; rr < 4; rr++)
                C[(size_t)(rbase + rr) * O_DIM + col] = acc[tt][jn][rr];
        }
    }
}

extern "C" void kernel_launch(void* const* d_in, const int* in_sizes, int n_in,
                              void* d_out, int out_size, void* d_ws, size_t ws_size,
                              hipStream_t stream) {
    const float* x  = (const float*)d_in[0];
    const float* bw = (const float*)d_in[1];
    const float* sw = (const float*)d_in[2];
    float* out = (float*)d_out;

    const size_t Wbytes = (size_t)O_DIM * K_DIM * sizeof(bf16);  // 4.7 MB
    if (ws_size < Wbytes) return;
    bf16* W = (bf16*)d_ws;

    pack_w_kernel<<<(O_DIM * 64 + 255) / 256, 256, 0, stream>>>(bw, sw, W);
    gemm_fused_kernel<<<dim3(B_ROWS / BM), 512, 0, stream>>>(x, W, out);
}

// Round 9
// 184.368 us; speedup vs baseline: 1.8940x; 1.8940x over previous
//
#include <hip/hip_runtime.h>
#include <cstdint>
#include <cstddef>
#include <type_traits>

#define B_ROWS 16384
#define D_DIM  512
#define O_DIM  512
#define K_DIM  4608    // 9 * 512: f=0 silu (base), f=1..8 spline channels
#define BM 64
#define BN 256
#define BK 32

typedef __bf16 bf16;
typedef __attribute__((ext_vector_type(8))) bf16  bf16x8;
typedef __attribute__((ext_vector_type(4))) float f32x4;

__device__ __forceinline__ void async_load16(const void* g, void* l) {
    __builtin_amdgcn_global_load_lds(
        (const __attribute__((address_space(1))) void*)g,
        (__attribute__((address_space(3))) void*)l,
        16, 0, 0);
}

__device__ __forceinline__ uint32_t pk2(float a, float b) {
    uint16_t ua = __builtin_bit_cast(uint16_t, (__bf16)a);
    uint16_t ub = __builtin_bit_cast(uint16_t, (__bf16)b);
    return (uint32_t)ua | ((uint32_t)ub << 16);
}

// Spline channels b0..b7 for one element as 4 packed bf16 pair-regs.
// out[j] = w_{j-s}, s = j0-3: 128-bit shift of [w3:w2:w1:w0] by 16*s bits
// (s in 0..10; s>=8 -> all zero, matches ref truncation for x>=1.2).
__device__ __forceinline__ void spline_pairs(float xv, uint32_t out[4]) {
    float xn = fminf(fmaxf(xv, -2.0f), 2.0f);
    float t  = (xn + 3.2f) * 2.5f;        // in [3,13]
    int   j0 = (int)t;                    // t>0 so trunc==floor
    float u  = t - (float)j0;
    float u2 = u * u, u3 = u2 * u, omu = 1.0f - u;
    const float s6 = 1.0f / 6.0f;
    float w0 = omu * omu * omu * s6;
    float w1 = (3.0f * u3 - 6.0f * u2 + 4.0f) * s6;
    float w2 = (-3.0f * u3 + 3.0f * u2 + 3.0f * u + 1.0f) * s6;
    float w3 = u3 * s6;
    uint64_t W64 = ((uint64_t)pk2(w2, w3) << 32) | pk2(w0, w1);
    int sh = (j0 - 3) * 16;               // 0..160
    uint64_t lo = W64 << (sh & 63);
    uint64_t hi = W64 >> ((64 - sh) & 63);
    uint32_t lo_lo = (uint32_t)lo, lo_hi = (uint32_t)(lo >> 32);
    uint32_t hi_lo = (uint32_t)hi, hi_hi = (uint32_t)(hi >> 32);
    bool lt64 = sh < 64, eq0 = (sh == 0), lt128 = sh < 128;
    out[0] = lt64 ? lo_lo : 0u;
    out[1] = lt64 ? lo_hi : 0u;
    out[2] = lt64 ? (eq0 ? 0u : hi_lo) : (lt128 ? lo_lo : 0u);
    out[3] = lt64 ? (eq0 ? 0u : hi_hi) : (lt128 ? lo_hi : 0u);
}

// base_weight[O,D] + spline_weight[O,D,8] fp32 -> W[O, 4608] bf16, k = f*512 + i
__global__ void pack_w_kernel(const float* __restrict__ bw,
                              const float* __restrict__ sw,
                              bf16* __restrict__ W) {
    int idx = blockIdx.x * blockDim.x + threadIdx.x;   // over O*64
    if (idx >= O_DIM * 64) return;
    int o  = idx >> 6;
    int i0 = (idx & 63) * 8;

    bf16 ob[9][8];
    const float* bwp = bw + (size_t)o * D_DIM + i0;
#pragma unroll
    for (int e = 0; e < 8; e++) {
        ob[0][e] = (bf16)bwp[e];
        const float* sp = sw + ((size_t)o * D_DIM + i0 + e) * 8;
#pragma unroll
        for (int c = 0; c < 8; c++)
            ob[c + 1][e] = (bf16)sp[c];
    }
    bf16* row = W + (size_t)o * K_DIM + i0;
#pragma unroll
    for (int f = 0; f < 9; f++)
        *(bf16x8*)(row + (size_t)f * D_DIM) = *(const bf16x8*)ob[f];
}

// Fused KAN GEMM (R5 structure). R9: break intra-step serialization --
// (a) 4 DISTINCT shared arrays so ds_read[cur] provably doesn't alias
// ds_write[cur^1] (one 2-indexed array defeated alias analysis),
// (b) issue af/bfr ds_reads FIRST in the step so featurize VALU runs under
// LDS latency, MFMA (lgkm-waiting) last before the barrier.
__global__ __launch_bounds__(256, 2)
void gemm_fused_kernel(const float* __restrict__ x, const bf16* __restrict__ W,
                       float* __restrict__ C) {
    __shared__ __align__(16) bf16 As0[BM * BK];   // 4 KB
    __shared__ __align__(16) bf16 As1[BM * BK];   // 4 KB
    __shared__ __align__(16) bf16 Bs0[BN * BK];   // 16 KB
    __shared__ __align__(16) bf16 Bs1[BN * BK];   // 16 KB

    const int tid  = threadIdx.x;
    const int n0   = blockIdx.x * BN;
    const int m0   = blockIdx.y * BM;
    const int wave = tid >> 6;
    const int lane = tid & 63;
    const int wn   = wave * 64;          // wave tile 64(all rows) x 64
    const int l15  = lane & 15;
    const int quad = lane >> 4;

    // featurize: thread owns (row rA, 8 i's at quarter q8 of the 32-chunk)
    const int rA = tid >> 2;             // 0..63
    const int q8 = tid & 3;
    const float* xrow = x + (size_t)(m0 + rA) * D_DIM + q8 * 8;
    const int aslot = q8 ^ ((rA >> 1) & 3);              // XOR slot swizzle
    const int awo = rA * BK + aslot * 8;
    bf16* aw0 = &As0[awo];
    bf16* aw1 = &As1[awo];

    // Bs staging: 4 rounds of 64 rows (2048 elements each), XOR-swizzled slot
    const int sr = tid >> 2;
    const int sc = ((tid & 3) ^ ((sr >> 1) & 3)) * 8;
    const bf16* gB = W + (size_t)(n0 + sr) * K_DIM + sc; // +j*64*K_DIM per round
    bf16* lb0 = &Bs0[tid * 8];
    bf16* lb1 = &Bs1[tid * 8];

    const int swz  = (l15 >> 1) & 3;
    const int aoff = l15 * BK + (quad ^ swz) * 8;
    const int boff = (wn + l15) * BK + (quad ^ swz) * 8;

    f32x4 acc[4][4] = {};
    uint32_t vpk[2][4][8];   // [chunk parity][channel-pair][element]
    float xe[8];

    // ---- prologue: chunk 0 features + step-(0,0) buffers ----
    {
        float4 a = *(const float4*)xrow;
        float4 b = *(const float4*)(xrow + 4);
        xe[0]=a.x; xe[1]=a.y; xe[2]=a.z; xe[3]=a.w;
        xe[4]=b.x; xe[5]=b.y; xe[6]=b.z; xe[7]=b.w;
#pragma unroll
        for (int e = 0; e < 8; e++) {
            uint32_t o4[4];
            spline_pairs(xe[e], o4);
            vpk[0][0][e]=o4[0]; vpk[0][1][e]=o4[1];
            vpk[0][2][e]=o4[2]; vpk[0][3][e]=o4[3];
        }
        float sl[8];
#pragma unroll
        for (int e = 0; e < 8; e++)
            sl[e] = xe[e] * __builtin_amdgcn_rcpf(1.0f + __expf(-xe[e]));
        uint32_t o[4] = {pk2(sl[0],sl[1]), pk2(sl[2],sl[3]),
                         pk2(sl[4],sl[5]), pk2(sl[6],sl[7])};
        *(uint4*)aw0 = *(const uint4*)o;
#pragma unroll
        for (int j = 0; j < 4; j++)
            async_load16(gB + (size_t)j * 64 * K_DIM, lb0 + j * 2048);
    }
    __syncthreads();

    auto chunk_body = [&](auto pcv, int c) {
        constexpr int PC = decltype(pcv)::value;
#pragma unroll
        for (int f = 0; f < 9; f++) {
            constexpr_int:;
            const int cur = (PC + f) & 1;          // compile-time after unroll
            const bf16* Asr = cur ? As1 : As0;
            const bf16* Bsr = cur ? Bs1 : Bs0;
            bf16* lbn = cur ? lb0 : lb1;           // next buffer
            bf16* awn = cur ? aw0 : aw1;
            const bool haveNext = !(c == 15 && f == 8);

            // (1) issue current-step fragment reads FIRST (latency overlaps
            //     the featurize VALU below; MFMA waits on lgkm at the end)
            bf16x8 af[4], bfr[4];
#pragma unroll
            for (int tt = 0; tt < 4; tt++)
                af[tt] = *(const bf16x8*)(Asr + aoff + tt * 16 * BK);
#pragma unroll
            for (int tt = 0; tt < 4; tt++)
                bfr[tt] = *(const bf16x8*)(Bsr + boff + tt * 16 * BK);

            // (2) B prefetch for next step (full step of flight)
            if (haveNext) {
                int koff = (f < 8) ? ((f + 1) * D_DIM + c * 32) : ((c + 1) * 32);
#pragma unroll
                for (int j = 0; j < 4; j++)
                    async_load16(gB + (size_t)j * 64 * K_DIM + koff, lbn + j * 2048);
            }
            // (3) x prefetch for chunk c+1
            if (f == 0 && c < 15) {
                float4 a = *(const float4*)(xrow + (c + 1) * 32);
                float4 b = *(const float4*)(xrow + (c + 1) * 32 + 4);
                xe[0]=a.x; xe[1]=a.y; xe[2]=a.z; xe[3]=a.w;
                xe[4]=b.x; xe[5]=b.y; xe[6]=b.z; xe[7]=b.w;
            }
            // (4) pipelined featurize: one element of chunk c+1 per step
            if (f >= 1 && c < 15) {
                uint32_t o4[4];
                spline_pairs(xe[f - 1], o4);
                vpk[PC ^ 1][0][f-1]=o4[0]; vpk[PC ^ 1][1][f-1]=o4[1];
                vpk[PC ^ 1][2][f-1]=o4[2]; vpk[PC ^ 1][3][f-1]=o4[3];
            }
            // (5) As write for next step: channel b_f of chunk c, or silu c+1
            if (haveNext) {
                uint32_t o[4];
                if (f < 8) {
                    const int pr = f >> 1;
#pragma unroll
                    for (int m = 0; m < 4; m++) {
                        uint32_t lo = vpk[PC][pr][2*m], hi = vpk[PC][pr][2*m+1];
                        o[m] = (f & 1) ? ((lo >> 16) | (hi & 0xFFFF0000u))
                                       : ((lo & 0xFFFFu) | (hi << 16));
                    }
                } else {
                    float sl[8];
#pragma unroll
                    for (int e = 0; e < 8; e++)
                        sl[e] = xe[e] * __builtin_amdgcn_rcpf(1.0f + __expf(-xe[e]));
                    o[0]=pk2(sl[0],sl[1]); o[1]=pk2(sl[2],sl[3]);
                    o[2]=pk2(sl[4],sl[5]); o[3]=pk2(sl[6],sl[7]);
                }
                *(uint4*)awn = *(const uint4*)o;
            }

            // (6) MFMA last
#pragma unroll
            for (int im = 0; im < 4; im++)
#pragma unroll
                for (int jn = 0; jn < 4; jn++)
                    acc[im][jn] = __builtin_amdgcn_mfma_f32_16x16x32_bf16(
                        af[im], bfr[jn], acc[im][jn], 0, 0, 0);
            __syncthreads();
        }
    };

    for (int cc = 0; cc < 16; cc += 2) {
        chunk_body(std::integral_constant<int,0>{}, cc);
        chunk_body(std::integral_constant<int,1>{}, cc + 1);
    }

    // C/D layout: col = lane&15, row = quad*4 + reg   [measured m89/m91]
#pragma unroll
    for (int im = 0; im < 4; im++) {
        const int rbase = m0 + im * 16 + quad * 4;
#pragma unroll
        for (int jn = 0; jn < 4; jn++) {
            const int col = n0 + wn + jn * 16 + l15;
#pragma unroll
            for (int rr = 0; rr < 4; rr++)
                C[(size_t)(rbase + rr) * O_DIM + col] = acc[im][jn][rr];
        }
    }
}

extern "C" void kernel_launch(void* const* d_in, const int* in_sizes, int n_in,
                              void* d_out, int out_size, void* d_ws, size_t ws_size,
                              hipStream_t stream) {
    const float* x  = (const float*)d_in[0];
    const float* bw = (const float*)d_in[1];
    const float* sw = (const float*)d_in[2];
    float* out = (float*)d_out;

    const size_t Wbytes = (size_t)O_DIM * K_DIM * sizeof(bf16);  // 4.7 MB
    if (ws_size < Wbytes) return;
    bf16* W = (bf16*)d_ws;

    pack_w_kernel<<<(O_DIM * 64 + 255) / 256, 256, 0, stream>>>(bw, sw, W);
    gemm_fused_kernel<<<dim3(O_DIM / BN, B_ROWS / BM), 256, 0, stream>>>(x, W, out);
}